// Round 3
// baseline (2179.899 us; speedup 1.0000x reference)
//
#include <hip/hip_runtime.h>
#include <math.h>

#define BATCH   512
#define TSTEPS  3600
#define H       64
#define CHUNK   180
#define NCHUNK  (TSTEPS / CHUNK)   // 20
#define CLASSES 5

__device__ __forceinline__ float lane_bcast(float v, int srclane) {
    // v_readlane_b32: broadcast lane `srclane` of v into an SGPR (uniform).
    return __builtin_bit_cast(float,
        __builtin_amdgcn_readlane(__builtin_bit_cast(int, v), srclane));
}

__device__ __forceinline__ float fast_sigmoid(float x) {
    // |x| <= ~10 by construction (|dot| bounded by sum|w| ~ 8) -> no clamp.
    float e = __expf(-x);
    return __builtin_amdgcn_rcpf(1.0f + e);
}

__device__ __forceinline__ float fast_tanh(float x) {
    float a = fabsf(x);
    float t = __expf(-2.0f * a);                    // in (0, 1], never overflows
    float r = (1.0f - t) * __builtin_amdgcn_rcpf(1.0f + t);
    return copysignf(r, x);
}

// ONE WAVE per batch element, ZERO LDS traffic in the h-recurrence.
// Lane i owns h_i and rows {i, 64+i, 128+i} of w_hh (straight layout, 192
// regs). Per step, h_j is broadcast to all lanes via v_readlane_b32 (64
// independent readlanes of the same register -> SGPRs), each feeding
// v_fmac_f32 with the SGPR as src0. Critical path is pure VALU issue
// (~285 instrs); the only LDS read is the per-step uniform x_t, hoisted to
// the top of the step so its latency hides under the fmac stream.
__global__ __launch_bounds__(64, 1) void gru_readlane_kernel(
    const float* __restrict__ x,      // [B, T, 1]
    const float* __restrict__ w_ih,   // [192, 1]
    const float* __restrict__ w_hh,   // [192, 64]
    const float* __restrict__ b_ih,   // [192]
    const float* __restrict__ b_hh,   // [192]
    const float* __restrict__ w_head, // [5, 64]
    const float* __restrict__ b_head, // [5]
    float* __restrict__ out)          // [B, 5]
{
    __shared__ float xl[CHUNK];

    const int lane = threadIdx.x;    // block = 1 wave
    const int b    = blockIdx.x;

    // --- recurrent weights: 3 rows x 64 = 192 floats per lane (registers) ---
    float w0[H], w1[H], w2[H];
#pragma unroll
    for (int j4 = 0; j4 < H / 4; ++j4) {
        float4 v0 = *(const float4*)(w_hh + (0 * H + lane) * H + 4 * j4);
        float4 v1 = *(const float4*)(w_hh + (1 * H + lane) * H + 4 * j4);
        float4 v2 = *(const float4*)(w_hh + (2 * H + lane) * H + 4 * j4);
        w0[4 * j4 + 0] = v0.x; w0[4 * j4 + 1] = v0.y; w0[4 * j4 + 2] = v0.z; w0[4 * j4 + 3] = v0.w;
        w1[4 * j4 + 0] = v1.x; w1[4 * j4 + 1] = v1.y; w1[4 * j4 + 2] = v1.z; w1[4 * j4 + 3] = v1.w;
        w2[4 * j4 + 0] = v2.x; w2[4 * j4 + 1] = v2.y; w2[4 * j4 + 2] = v2.z; w2[4 * j4 + 3] = v2.w;
    }

    const float wih_r = w_ih[lane], wih_z = w_ih[H + lane], wih_n = w_ih[2 * H + lane];
    const float bih_r = b_ih[lane], bih_z = b_ih[H + lane], bih_n = b_ih[2 * H + lane];
    const float bhh_r = b_hh[lane], bhh_z = b_hh[H + lane], bhh_n = b_hh[2 * H + lane];

    float h_reg = 0.0f;
    const float* xb = x + (size_t)b * TSTEPS;

    for (int c = 0; c < NCHUNK; ++c) {
        // stage this chunk of x (wave-synchronous; same-wave DS ordering)
#pragma unroll
        for (int k = 0; k < 3; ++k) {
            int idx = lane + 64 * k;
            if (idx < CHUNK) xl[idx] = xb[c * CHUNK + idx];
        }

        for (int tt = 0; tt < CHUNK; ++tt) {
            const float xt = xl[tt];     // hoisted: ~500 cyc of slack below

            // two accumulators per gate (even/odd j) -> dep chains of 32
            float arA = bhh_r, arB = 0.f;
            float azA = bhh_z, azB = 0.f;
            float anA = bhh_n, anB = 0.f;
#pragma unroll
            for (int j = 0; j < H; j += 2) {
                const float hjA = lane_bcast(h_reg, j);
                const float hjB = lane_bcast(h_reg, j + 1);
                arA = fmaf(hjA, w0[j],     arA);
                azA = fmaf(hjA, w1[j],     azA);
                anA = fmaf(hjA, w2[j],     anA);
                arB = fmaf(hjB, w0[j + 1], arB);
                azB = fmaf(hjB, w1[j + 1], azB);
                anB = fmaf(hjB, w2[j + 1], anB);
            }
            const float dr = arA + arB;
            const float dz = azA + azB;
            const float dn = anA + anB;

            const float r = fast_sigmoid(fmaf(xt, wih_r, bih_r) + dr);
            const float z = fast_sigmoid(fmaf(xt, wih_z, bih_z) + dz);
            const float n = fast_tanh(fmaf(xt, wih_n, bih_n) + r * dn);
            h_reg = fmaf(z, h_reg - n, n);   // (1-z)*n + z*h
        }
    }

    // ---- head: out[b][c] = w_head[c,:] . h + b_head[c] ----
#pragma unroll
    for (int cc = 0; cc < CLASSES; ++cc) {
        float v = h_reg * w_head[cc * H + lane];
#pragma unroll
        for (int off = 32; off > 0; off >>= 1)
            v += __shfl_down(v, off, 64);
        if (lane == 0) out[b * CLASSES + cc] = v + b_head[cc];
    }
}

extern "C" void kernel_launch(void* const* d_in, const int* in_sizes, int n_in,
                              void* d_out, int out_size, void* d_ws, size_t ws_size,
                              hipStream_t stream) {
    const float* x      = (const float*)d_in[0];
    const float* w_ih   = (const float*)d_in[1];
    const float* w_hh   = (const float*)d_in[2];
    const float* b_ih   = (const float*)d_in[3];
    const float* b_hh   = (const float*)d_in[4];
    const float* w_head = (const float*)d_in[5];
    const float* b_head = (const float*)d_in[6];
    float* out = (float*)d_out;

    gru_readlane_kernel<<<BATCH, 64, 0, stream>>>(x, w_ih, w_hh, b_ih, b_hh,
                                                  w_head, b_head, out);
}

// Round 4
// 1695.850 us; speedup vs baseline: 1.2854x; 1.2854x over previous
//
#include <hip/hip_runtime.h>
#include <math.h>

#define BATCH   512
#define TSTEPS  3600
#define H       64
#define CHUNK   180
#define NCHUNK  (TSTEPS / CHUNK)   // 20
#define CLASSES 5

typedef float v2f __attribute__((ext_vector_type(2)));

__device__ __forceinline__ float fast_sigmoid(float x) {
    float e = __expf(-x);
    return __builtin_amdgcn_rcpf(1.0f + e);
}

__device__ __forceinline__ float fast_tanh(float x) {
    float a = fabsf(x);
    float t = __expf(-2.0f * a);                    // in (0, 1], never overflows
    float r = (1.0f - t) * __builtin_amdgcn_rcpf(1.0f + t);
    return copysignf(r, x);
}

// ONE WAVE per batch. h broadcast via LDS (wave-uniform ds_read_b128, no
// barriers, no bank conflicts). Dot products in PACKED fp32 (v_pk_fma_f32,
// full-rate on CDNA): 96 pk_fma/step instead of 192 fmac. Six independent
// packed accumulator chains keep dep-latency off the critical path and let
// the 16 broadcast reads pipeline against consumption. This is a latency
// race: per-batch chain = 3600 serial steps; occupancy doesn't matter.
__global__ __launch_bounds__(64, 1) void gru_pk_kernel(
    const float* __restrict__ x,      // [B, T, 1]
    const float* __restrict__ w_ih,   // [192, 1]
    const float* __restrict__ w_hh,   // [192, 64]
    const float* __restrict__ b_ih,   // [192]
    const float* __restrict__ b_hh,   // [192]
    const float* __restrict__ w_head, // [5, 64]
    const float* __restrict__ b_head, // [5]
    float* __restrict__ out)          // [B, 5]
{
    __shared__ __align__(16) float hl[H];
    __shared__ float xl[CHUNK];

    const int lane = threadIdx.x;    // block = 1 wave
    const int b    = blockIdx.x;

    // --- recurrent weights: rows {lane, 64+lane, 128+lane}, as float2 pairs ---
    v2f w0A[H / 4], w0B[H / 4], w1A[H / 4], w1B[H / 4], w2A[H / 4], w2B[H / 4];
#pragma unroll
    for (int j4 = 0; j4 < H / 4; ++j4) {
        float4 v0 = *(const float4*)(w_hh + (0 * H + lane) * H + 4 * j4);
        float4 v1 = *(const float4*)(w_hh + (1 * H + lane) * H + 4 * j4);
        float4 v2 = *(const float4*)(w_hh + (2 * H + lane) * H + 4 * j4);
        w0A[j4] = (v2f){v0.x, v0.y};  w0B[j4] = (v2f){v0.z, v0.w};
        w1A[j4] = (v2f){v1.x, v1.y};  w1B[j4] = (v2f){v1.z, v1.w};
        w2A[j4] = (v2f){v2.x, v2.y};  w2B[j4] = (v2f){v2.z, v2.w};
    }

    const float wih_r = w_ih[lane], wih_z = w_ih[H + lane], wih_n = w_ih[2 * H + lane];
    const float bih_r = b_ih[lane], bih_z = b_ih[H + lane], bih_n = b_ih[2 * H + lane];
    const float bhh_r = b_hh[lane], bhh_z = b_hh[H + lane], bhh_n = b_hh[2 * H + lane];

    float h_reg = 0.0f;
    const float* xb = x + (size_t)b * TSTEPS;

    for (int c = 0; c < NCHUNK; ++c) {
        // stage this chunk of x (wave-synchronous; same-wave DS ordering)
#pragma unroll
        for (int k = 0; k < 3; ++k) {
            int idx = lane + 64 * k;
            if (idx < CHUNK) xl[idx] = xb[c * CHUNK + idx];
        }

        for (int tt = 0; tt < CHUNK; ++tt) {
            hl[lane] = h_reg;            // publish h_i (one ds_write_b32)
            const float xt = xl[tt];     // uniform; hides under the dot

            // 6 independent packed accumulator chains (16 pk_fma each)
            v2f arA = (v2f){bhh_r, 0.f}, arB = (v2f){0.f, 0.f};
            v2f azA = (v2f){bhh_z, 0.f}, azB = (v2f){0.f, 0.f};
            v2f anA = (v2f){bhh_n, 0.f}, anB = (v2f){0.f, 0.f};
            const float4* hp = (const float4*)hl;
#pragma unroll
            for (int j4 = 0; j4 < H / 4; ++j4) {
                float4 h4 = hp[j4];                       // wave-uniform broadcast
                v2f hA; hA.x = h4.x; hA.y = h4.y;
                v2f hB; hB.x = h4.z; hB.y = h4.w;
                arA = __builtin_elementwise_fma(w0A[j4], hA, arA);
                azA = __builtin_elementwise_fma(w1A[j4], hA, azA);
                anA = __builtin_elementwise_fma(w2A[j4], hA, anA);
                arB = __builtin_elementwise_fma(w0B[j4], hB, arB);
                azB = __builtin_elementwise_fma(w1B[j4], hB, azB);
                anB = __builtin_elementwise_fma(w2B[j4], hB, anB);
            }
            v2f vr = arA + arB, vz = azA + azB, vn = anA + anB;
            const float dr = vr.x + vr.y;
            const float dz = vz.x + vz.y;
            const float dn = vn.x + vn.y;

            const float r = fast_sigmoid(fmaf(xt, wih_r, bih_r) + dr);
            const float z = fast_sigmoid(fmaf(xt, wih_z, bih_z) + dz);
            const float n = fast_tanh(fmaf(xt, wih_n, bih_n) + r * dn);
            h_reg = fmaf(z, h_reg - n, n);   // (1-z)*n + z*h
        }
    }

    // ---- head: out[b][c] = w_head[c,:] . h + b_head[c] ----
#pragma unroll
    for (int cc = 0; cc < CLASSES; ++cc) {
        float v = h_reg * w_head[cc * H + lane];
#pragma unroll
        for (int off = 32; off > 0; off >>= 1)
            v += __shfl_down(v, off, 64);
        if (lane == 0) out[b * CLASSES + cc] = v + b_head[cc];
    }
}

extern "C" void kernel_launch(void* const* d_in, const int* in_sizes, int n_in,
                              void* d_out, int out_size, void* d_ws, size_t ws_size,
                              hipStream_t stream) {
    const float* x      = (const float*)d_in[0];
    const float* w_ih   = (const float*)d_in[1];
    const float* w_hh   = (const float*)d_in[2];
    const float* b_ih   = (const float*)d_in[3];
    const float* b_hh   = (const float*)d_in[4];
    const float* w_head = (const float*)d_in[5];
    const float* b_head = (const float*)d_in[6];
    float* out = (float*)d_out;

    gru_pk_kernel<<<BATCH, 64, 0, stream>>>(x, w_ih, w_hh, b_ih, b_hh,
                                            w_head, b_head, out);
}

// Round 5
// 1572.250 us; speedup vs baseline: 1.3865x; 1.0786x over previous
//
#include <hip/hip_runtime.h>
#include <math.h>

#define BATCH   512
#define TSTEPS  3600
#define H       64
#define CHUNK   180
#define NCHUNK  (TSTEPS / CHUNK)   // 20
#define CLASSES 5

typedef float v2f __attribute__((ext_vector_type(2)));

// GFX9 DPP full-wave rotates: lane i reads lane (i-1)&63 (ror) / (i+1)&63 (rol)
#define DPP_WAVE_ROR1 0x13C
#define DPP_WAVE_ROL1 0x134

__device__ __forceinline__ float dpp_ror1(float v) {
    int i = __builtin_bit_cast(int, v);
    return __builtin_bit_cast(float,
        __builtin_amdgcn_update_dpp(i, i, DPP_WAVE_ROR1, 0xF, 0xF, false));
}
__device__ __forceinline__ float dpp_rol1(float v) {
    int i = __builtin_bit_cast(int, v);
    return __builtin_bit_cast(float,
        __builtin_amdgcn_update_dpp(i, i, DPP_WAVE_ROL1, 0xF, 0xF, false));
}

__device__ __forceinline__ float fast_sigmoid(float x) {
    // |x| <= ~9 by construction -> no clamp needed
    float e = __expf(-x);
    return __builtin_amdgcn_rcpf(1.0f + e);
}
__device__ __forceinline__ float fast_tanh(float x) {
    // tanh(x) = (e-1)/(e+1), e = exp(2x); |2x| <= ~18 -> no overflow
    float e = __expf(2.0f * x);
    return (e - 1.0f) * __builtin_amdgcn_rcpf(e + 1.0f);
}

// ONE WAVE per batch; the h-recurrence touches NO LDS (R2/R4 showed the LDS
// round-trip costs ~600+ cyc/step from landing-register starvation).
// Systolic broadcast: two register streams of h rotate through the wave via
// DPP (wave_ror:1 / wave_rol:1, plain VALU ops). Stream x covers j=i..i-31,
// stream y (pre-rotated once) covers j=i+1..i+32. Weights are loaded
// pre-permuted per lane so register indexing stays uniform, packed as
// float2 so the dot is 96 v_pk_fma_f32 + 62 dpp movs per step, pure issue.
__global__ __launch_bounds__(64, 1) void gru_dpp_kernel(
    const float* __restrict__ x,      // [B, T, 1]
    const float* __restrict__ w_ih,   // [192, 1]
    const float* __restrict__ w_hh,   // [192, 64]
    const float* __restrict__ b_ih,   // [192]
    const float* __restrict__ b_hh,   // [192]
    const float* __restrict__ w_head, // [5, 64]
    const float* __restrict__ b_head, // [5]
    float* __restrict__ out)          // [B, 5]
{
    __shared__ float xl[CHUNK];

    const int lane = threadIdx.x;    // block = 1 wave
    const int b    = blockIdx.x;

    // --- recurrent weights, pre-permuted for the rotation schedule ---
    // wr/wz/wn[u] = { row[(lane-u)&63], row[(lane+1+u)&63] }
    const float* row_r = w_hh + (0 * H + lane) * H;
    const float* row_z = w_hh + (1 * H + lane) * H;
    const float* row_n = w_hh + (2 * H + lane) * H;
    v2f wr[32], wz[32], wn[32];
#pragma unroll
    for (int u = 0; u < 32; ++u) {
        const int jx = (lane - u) & 63;
        const int jy = (lane + 1 + u) & 63;
        wr[u] = (v2f){row_r[jx], row_r[jy]};
        wz[u] = (v2f){row_z[jx], row_z[jy]};
        wn[u] = (v2f){row_n[jx], row_n[jy]};
    }

    const float wih_r = w_ih[lane], wih_z = w_ih[H + lane], wih_n = w_ih[2 * H + lane];
    const float bih_r = b_ih[lane], bih_z = b_ih[H + lane], bih_n = b_ih[2 * H + lane];
    const float bhh_r = b_hh[lane], bhh_z = b_hh[H + lane], bhh_n = b_hh[2 * H + lane];

    float h_reg = 0.0f;
    const float* xb = x + (size_t)b * TSTEPS;

    for (int c = 0; c < NCHUNK; ++c) {
        // stage this chunk of x (wave-synchronous; same-wave DS ordering)
#pragma unroll
        for (int k = 0; k < 3; ++k) {
            int idx = lane + 64 * k;
            if (idx < CHUNK) xl[idx] = xb[c * CHUNK + idx];
        }

        for (int tt = 0; tt < CHUNK; ++tt) {
            const float xt = xl[tt];   // only LDS op in the step; consumed late

            v2f hh;                    // two rotating h streams
            hh.x = h_reg;              // j = lane
            hh.y = dpp_rol1(h_reg);    // j = lane+1

            v2f ar = (v2f){bhh_r, 0.f};
            v2f az = (v2f){bhh_z, 0.f};
            v2f an = (v2f){bhh_n, 0.f};
#pragma unroll
            for (int u = 0; u < 32; ++u) {
                ar = __builtin_elementwise_fma(wr[u], hh, ar);
                az = __builtin_elementwise_fma(wz[u], hh, az);
                an = __builtin_elementwise_fma(wn[u], hh, an);
                if (u < 31) {
                    hh.x = dpp_ror1(hh.x);   // j: lane-u -> lane-u-1
                    hh.y = dpp_rol1(hh.y);   // j: lane+1+u -> lane+2+u
                }
            }
            const float dr = ar.x + ar.y;
            const float dz = az.x + az.y;
            const float dn = an.x + an.y;

            const float r = fast_sigmoid(fmaf(xt, wih_r, bih_r) + dr);
            const float z = fast_sigmoid(fmaf(xt, wih_z, bih_z) + dz);
            const float n = fast_tanh(fmaf(xt, wih_n, bih_n) + r * dn);
            h_reg = fmaf(z, h_reg - n, n);   // (1-z)*n + z*h
        }
    }

    // ---- head: out[b][c] = w_head[c,:] . h + b_head[c] ----
#pragma unroll
    for (int cc = 0; cc < CLASSES; ++cc) {
        float v = h_reg * w_head[cc * H + lane];
#pragma unroll
        for (int off = 32; off > 0; off >>= 1)
            v += __shfl_down(v, off, 64);
        if (lane == 0) out[b * CLASSES + cc] = v + b_head[cc];
    }
}

extern "C" void kernel_launch(void* const* d_in, const int* in_sizes, int n_in,
                              void* d_out, int out_size, void* d_ws, size_t ws_size,
                              hipStream_t stream) {
    const float* x      = (const float*)d_in[0];
    const float* w_ih   = (const float*)d_in[1];
    const float* w_hh   = (const float*)d_in[2];
    const float* b_ih   = (const float*)d_in[3];
    const float* b_hh   = (const float*)d_in[4];
    const float* w_head = (const float*)d_in[5];
    const float* b_head = (const float*)d_in[6];
    float* out = (float*)d_out;

    gru_dpp_kernel<<<BATCH, 64, 0, stream>>>(x, w_ih, w_hh, b_ih, b_hh,
                                             w_head, b_head, out);
}

// Round 6
// 1538.673 us; speedup vs baseline: 1.4167x; 1.0218x over previous
//
#include <hip/hip_runtime.h>
#include <math.h>

#define BATCH   512
#define TSTEPS  3600
#define H       64
#define XCHUNK  8
#define CLASSES 5

__device__ __forceinline__ float lane_bcast(float v, int srclane) {
    return __builtin_bit_cast(float,
        __builtin_amdgcn_readlane(__builtin_bit_cast(int, v), srclane));
}

__device__ __forceinline__ float fast_sigmoid(float x) {
    float e = __expf(-x);
    return __builtin_amdgcn_rcpf(1.0f + e);
}
__device__ __forceinline__ float fast_tanh(float x) {
    float e = __expf(2.0f * x);        // |2x| <= ~18, no overflow
    return (e - 1.0f) * __builtin_amdgcn_rcpf(e + 1.0f);
}

// ONE WAVE per batch; ZERO LDS; h broadcast via BURST v_readlane.
// R3's readlane failed on the VALU->SGPR->VALU hazard because each readlane
// was consumed ~2 instructions later. Here all 32 readlanes of a half issue
// as one burst (they are independent - all read h_reg), and sched_barrier(0)
// pins the 96 consuming fmacs after the burst: every SGPR's first use is
// >=32 instructions past its write, so all hazards are hidden by issue
// distance and - unlike R5's DPP rotation - there is NO serial chain.
// x[t] is wave-uniform -> loaded via uniform s_load (SGPRs), no LDS at all.
__global__ __launch_bounds__(64, 1) void gru_rl_burst_kernel(
    const float* __restrict__ x,      // [B, T, 1]
    const float* __restrict__ w_ih,   // [192, 1]
    const float* __restrict__ w_hh,   // [192, 64]
    const float* __restrict__ b_ih,   // [192]
    const float* __restrict__ b_hh,   // [192]
    const float* __restrict__ w_head, // [5, 64]
    const float* __restrict__ b_head, // [5]
    float* __restrict__ out)          // [B, 5]
{
    const int lane = threadIdx.x;    // block = 1 wave
    const int b    = blockIdx.x;

    // --- recurrent weights: rows {lane, 64+lane, 128+lane} in registers ---
    float w0[H], w1[H], w2[H];
#pragma unroll
    for (int j4 = 0; j4 < H / 4; ++j4) {
        float4 v0 = *(const float4*)(w_hh + (0 * H + lane) * H + 4 * j4);
        float4 v1 = *(const float4*)(w_hh + (1 * H + lane) * H + 4 * j4);
        float4 v2 = *(const float4*)(w_hh + (2 * H + lane) * H + 4 * j4);
        w0[4 * j4 + 0] = v0.x; w0[4 * j4 + 1] = v0.y; w0[4 * j4 + 2] = v0.z; w0[4 * j4 + 3] = v0.w;
        w1[4 * j4 + 0] = v1.x; w1[4 * j4 + 1] = v1.y; w1[4 * j4 + 2] = v1.z; w1[4 * j4 + 3] = v1.w;
        w2[4 * j4 + 0] = v2.x; w2[4 * j4 + 1] = v2.y; w2[4 * j4 + 2] = v2.z; w2[4 * j4 + 3] = v2.w;
    }

    const float wih_r = w_ih[lane], wih_z = w_ih[H + lane], wih_n = w_ih[2 * H + lane];
    const float bih_r = b_ih[lane], bih_z = b_ih[H + lane], bih_n = b_ih[2 * H + lane];
    const float bhh_r = b_hh[lane], bhh_z = b_hh[H + lane], bhh_n = b_hh[2 * H + lane];

    float h_reg = 0.0f;
    const float* xb = x + (size_t)b * TSTEPS;

    for (int tc = 0; tc < TSTEPS / XCHUNK; ++tc) {
        // x chunk via uniform loads -> SGPRs (s_load_dwordx8), no LDS
        float xs[XCHUNK];
#pragma unroll
        for (int k = 0; k < XCHUNK; ++k) xs[k] = xb[tc * XCHUNK + k];

#pragma unroll
        for (int tt = 0; tt < XCHUNK; ++tt) {
            const float xt = xs[tt];

            float ar0 = bhh_r, az0 = bhh_z, an0 = bhh_n;
            float ar1 = 0.f,   az1 = 0.f,   an1 = 0.f;

            // ---- half 1: j = 0..31 ----
            {
                float hs[32];
#pragma unroll
                for (int j = 0; j < 32; ++j) hs[j] = lane_bcast(h_reg, j);
                __builtin_amdgcn_sched_barrier(0);
#pragma unroll
                for (int j = 0; j < 32; ++j) {
                    ar0 = fmaf(hs[j], w0[j], ar0);
                    az0 = fmaf(hs[j], w1[j], az0);
                    an0 = fmaf(hs[j], w2[j], an0);
                }
                __builtin_amdgcn_sched_barrier(0);
            }
            // ---- half 2: j = 32..63 ----
            {
                float hs[32];
#pragma unroll
                for (int j = 0; j < 32; ++j) hs[j] = lane_bcast(h_reg, j + 32);
                __builtin_amdgcn_sched_barrier(0);
#pragma unroll
                for (int j = 0; j < 32; ++j) {
                    ar1 = fmaf(hs[j], w0[j + 32], ar1);
                    az1 = fmaf(hs[j], w1[j + 32], az1);
                    an1 = fmaf(hs[j], w2[j + 32], an1);
                }
                __builtin_amdgcn_sched_barrier(0);
            }

            const float dr = ar0 + ar1;
            const float dz = az0 + az1;
            const float dn = an0 + an1;

            const float r = fast_sigmoid(fmaf(xt, wih_r, bih_r) + dr);
            const float z = fast_sigmoid(fmaf(xt, wih_z, bih_z) + dz);
            const float n = fast_tanh(fmaf(xt, wih_n, bih_n) + r * dn);
            h_reg = fmaf(z, h_reg - n, n);   // (1-z)*n + z*h
        }
    }

    // ---- head: out[b][c] = w_head[c,:] . h + b_head[c] ----
#pragma unroll
    for (int cc = 0; cc < CLASSES; ++cc) {
        float v = h_reg * w_head[cc * H + lane];
#pragma unroll
        for (int off = 32; off > 0; off >>= 1)
            v += __shfl_down(v, off, 64);
        if (lane == 0) out[b * CLASSES + cc] = v + b_head[cc];
    }
}

extern "C" void kernel_launch(void* const* d_in, const int* in_sizes, int n_in,
                              void* d_out, int out_size, void* d_ws, size_t ws_size,
                              hipStream_t stream) {
    const float* x      = (const float*)d_in[0];
    const float* w_ih   = (const float*)d_in[1];
    const float* w_hh   = (const float*)d_in[2];
    const float* b_ih   = (const float*)d_in[3];
    const float* b_hh   = (const float*)d_in[4];
    const float* w_head = (const float*)d_in[5];
    const float* b_head = (const float*)d_in[6];
    float* out = (float*)d_out;

    gru_rl_burst_kernel<<<BATCH, 64, 0, stream>>>(x, w_ih, w_hh, b_ih, b_hh,
                                                  w_head, b_head, out);
}

// Round 7
// 1496.333 us; speedup vs baseline: 1.4568x; 1.0283x over previous
//
#include <hip/hip_runtime.h>
#include <math.h>

#define BATCH   512
#define TSTEPS  3600
#define H       64
#define XCHUNK  8
#define CLASSES 5

typedef float v2f __attribute__((ext_vector_type(2)));

__device__ __forceinline__ float lane_bcast(float v, int srclane) {
    return __builtin_bit_cast(float,
        __builtin_amdgcn_readlane(__builtin_bit_cast(int, v), srclane));
}

__device__ __forceinline__ float fast_sigmoid(float x) {
    float e = __expf(-x);
    return __builtin_amdgcn_rcpf(1.0f + e);
}
__device__ __forceinline__ float fast_tanh(float x) {
    float e = __expf(2.0f * x);        // |2x| <= ~18, no overflow
    return (e - 1.0f) * __builtin_amdgcn_rcpf(e + 1.0f);
}

// ONE WAVE per batch; ZERO LDS; h broadcast via readlane PAIRS feeding
// v_pk_fma_f32 (halves dot issue: 96 pk instead of 192 fmac). The pair
// {h_2u, h_2u+1} is wave-uniform -> SGPR pair, legal as the single 64-bit
// scalar operand of VOP3P. Two half-bursts of 16 pairs bound SGPR pressure.
// Gate-ordered dots: the r-gate finishes first so its sigmoid latency hides
// under the z/n pk_fma stream; only the n-tanh tail stays exposed.
// This is a latency race (1 wave/SIMD, 3600 serial steps); occupancy is
// irrelevant - only the per-step dependency chain length matters.
__global__ __launch_bounds__(64, 1) void gru_pk_rl_kernel(
    const float* __restrict__ x,      // [B, T, 1]
    const float* __restrict__ w_ih,   // [192, 1]
    const float* __restrict__ w_hh,   // [192, 64]
    const float* __restrict__ b_ih,   // [192]
    const float* __restrict__ b_hh,   // [192]
    const float* __restrict__ w_head, // [5, 64]
    const float* __restrict__ b_head, // [5]
    float* __restrict__ out)          // [B, 5]
{
    const int lane = threadIdx.x;    // block = 1 wave
    const int b    = blockIdx.x;

    // --- recurrent weights as packed pairs: wg[u] = {row[2u], row[2u+1]} ---
    v2f wr[32], wz[32], wn[32];
#pragma unroll
    for (int u = 0; u < 32; ++u) {
        wr[u] = *(const v2f*)(w_hh + (0 * H + lane) * H + 2 * u);
        wz[u] = *(const v2f*)(w_hh + (1 * H + lane) * H + 2 * u);
        wn[u] = *(const v2f*)(w_hh + (2 * H + lane) * H + 2 * u);
    }

    const float wih_r = w_ih[lane], wih_z = w_ih[H + lane], wih_n = w_ih[2 * H + lane];
    const float bih_r = b_ih[lane], bih_z = b_ih[H + lane], bih_n = b_ih[2 * H + lane];
    const float bhh_r = b_hh[lane], bhh_z = b_hh[H + lane], bhh_n = b_hh[2 * H + lane];

    float h_reg = 0.0f;
    const float* xb = x + (size_t)b * TSTEPS;

    for (int tc = 0; tc < TSTEPS / XCHUNK; ++tc) {
        // x chunk via uniform loads -> SGPRs, no LDS
        float xs[XCHUNK];
#pragma unroll
        for (int k = 0; k < XCHUNK; ++k) xs[k] = xb[tc * XCHUNK + k];

#pragma unroll
        for (int tt = 0; tt < XCHUNK; ++tt) {
            const float xt = xs[tt];

            // accumulator chains: 2 per gate (even/odd u), depth 16 each
            v2f arA = (v2f){bhh_r, 0.f}, arB = (v2f){0.f, 0.f};
            v2f azA = (v2f){bhh_z, 0.f}, azB = (v2f){0.f, 0.f};
            v2f anA = (v2f){bhh_n, 0.f}, anB = (v2f){0.f, 0.f};

            // ---- half 1: pairs u = 0..15 (j = 0..31) ----
            v2f hp1[16];
#pragma unroll
            for (int u = 0; u < 16; ++u) {
                hp1[u].x = lane_bcast(h_reg, 2 * u);
                hp1[u].y = lane_bcast(h_reg, 2 * u + 1);
            }
#pragma unroll
            for (int u = 0; u < 16; u += 2) {
                arA = __builtin_elementwise_fma(wr[u],     hp1[u],     arA);
                arB = __builtin_elementwise_fma(wr[u + 1], hp1[u + 1], arB);
            }
#pragma unroll
            for (int u = 0; u < 16; u += 2) {
                azA = __builtin_elementwise_fma(wz[u],     hp1[u],     azA);
                azB = __builtin_elementwise_fma(wz[u + 1], hp1[u + 1], azB);
                anA = __builtin_elementwise_fma(wn[u],     hp1[u],     anA);
                anB = __builtin_elementwise_fma(wn[u + 1], hp1[u + 1], anB);
            }

            // ---- half 2: pairs u = 16..31 (j = 32..63) ----
            v2f hp2[16];
#pragma unroll
            for (int u = 0; u < 16; ++u) {
                hp2[u].x = lane_bcast(h_reg, 32 + 2 * u);
                hp2[u].y = lane_bcast(h_reg, 32 + 2 * u + 1);
            }
            // r-gate first: its sigmoid latency hides under the z/n stream
#pragma unroll
            for (int u = 0; u < 16; u += 2) {
                arA = __builtin_elementwise_fma(wr[16 + u],     hp2[u],     arA);
                arB = __builtin_elementwise_fma(wr[16 + u + 1], hp2[u + 1], arB);
            }
            v2f vr = arA + arB;
            const float r = fast_sigmoid(fmaf(xt, wih_r, bih_r) + vr.x + vr.y);

#pragma unroll
            for (int u = 0; u < 16; u += 2) {
                azA = __builtin_elementwise_fma(wz[16 + u],     hp2[u],     azA);
                azB = __builtin_elementwise_fma(wz[16 + u + 1], hp2[u + 1], azB);
            }
            v2f vz = azA + azB;
            const float z = fast_sigmoid(fmaf(xt, wih_z, bih_z) + vz.x + vz.y);

#pragma unroll
            for (int u = 0; u < 16; u += 2) {
                anA = __builtin_elementwise_fma(wn[16 + u],     hp2[u],     anA);
                anB = __builtin_elementwise_fma(wn[16 + u + 1], hp2[u + 1], anB);
            }
            v2f vn = anA + anB;
            const float n = fast_tanh(fmaf(xt, wih_n, bih_n) + r * (vn.x + vn.y));

            h_reg = fmaf(z, h_reg - n, n);   // (1-z)*n + z*h
        }
    }

    // ---- head: out[b][c] = w_head[c,:] . h + b_head[c] ----
#pragma unroll
    for (int cc = 0; cc < CLASSES; ++cc) {
        float v = h_reg * w_head[cc * H + lane];
#pragma unroll
        for (int off = 32; off > 0; off >>= 1)
            v += __shfl_down(v, off, 64);
        if (lane == 0) out[b * CLASSES + cc] = v + b_head[cc];
    }
}

extern "C" void kernel_launch(void* const* d_in, const int* in_sizes, int n_in,
                              void* d_out, int out_size, void* d_ws, size_t ws_size,
                              hipStream_t stream) {
    const float* x      = (const float*)d_in[0];
    const float* w_ih   = (const float*)d_in[1];
    const float* w_hh   = (const float*)d_in[2];
    const float* b_ih   = (const float*)d_in[3];
    const float* b_hh   = (const float*)d_in[4];
    const float* w_head = (const float*)d_in[5];
    const float* b_head = (const float*)d_in[6];
    float* out = (float*)d_out;

    gru_pk_rl_kernel<<<BATCH, 64, 0, stream>>>(x, w_ih, w_hh, b_ih, b_hh,
                                               w_head, b_head, out);
}